// Round 2
// baseline (51.841 us; speedup 1.0000x reference)
//
#include <hip/hip_runtime.h>

#define NROWS 8192
#define DIM   256          // elements per row == bytes per row in fp8
#define BHALF 4096
#define NTILE 64           // 8192 / 128
#define BM    128
#define SQRT2 1.41421356237f

typedef unsigned char u8;
typedef __attribute__((ext_vector_type(4))) float f32x4;
typedef __attribute__((ext_vector_type(4))) int   i32x4;
typedef __attribute__((ext_vector_type(8))) int   i32x8;

// exact xor-butterfly add via DPP quad_perm (VALU, not DS pipe)
template <int CTRL>
__device__ inline float qp_add(float s) {
  int si = __builtin_bit_cast(int, s);
  int v = __builtin_amdgcn_update_dpp(si, si, CTRL, 0xF, 0xF, false);
  return s + __builtin_bit_cast(float, v);
}

// Kernel 1: row-normalize concat(z_i, z_j), scale by sqrt(2) so dot = cos/TEMP,
// emit fp8 e4m3 Zn8 [8192][256] (2 MB; fits in each XCD's 4MB L2).
// Also zeroes the output scalar (stream-ordered before fin's atomics).
__global__ __launch_bounds__(256) void nrm_kernel(const float* __restrict__ zi,
                                                  const float* __restrict__ zj,
                                                  u8* __restrict__ zn8,
                                                  float* __restrict__ out) {
  if (blockIdx.x == 0 && threadIdx.x == 0) out[0] = 0.f;
  const int w = threadIdx.x >> 6, l = threadIdx.x & 63;
  const int row = blockIdx.x * 4 + w;
  const float* src = (row < BHALF) ? zi + (size_t)row * DIM
                                   : zj + (size_t)(row - BHALF) * DIM;
  float4 v = *(const float4*)(src + l * 4);
  float ss = v.x * v.x + v.y * v.y + v.z * v.z + v.w * v.w;
#pragma unroll
  for (int m = 1; m < 64; m <<= 1) ss += __shfl_xor(ss, m);
  float inv = SQRT2 / fmaxf(sqrtf(ss), 1e-8f);
  int p = __builtin_amdgcn_cvt_pk_fp8_f32(v.x * inv, v.y * inv, 0, false);
  p = __builtin_amdgcn_cvt_pk_fp8_f32(v.z * inv, v.w * inv, p, true);
  *(int*)(zn8 + (size_t)row * DIM + (size_t)l * 4) = p;
}

// Kernel 2: upper-triangle 128x128 Gram tiles, MX-scaled fp8 MFMA (K=128,
// unit e8m0 scales). NO LDS staging: zn8 (2 MB) is L2-resident per XCD, so
// MFMA fragments load straight from global (L2 hit). No barriers in the
// main loop; 2 KB LDS only for the epilogue reduce planes.
__global__ __launch_bounds__(256, 2) void sim_kernel(const u8* __restrict__ zn8,
                                                     float* __restrict__ partials,
                                                     float* __restrict__ pos) {
  __shared__ float brs_rw[2][BM];   // [wc][row]  per-wave-plane, no atomics
  __shared__ float brs_cw[2][BM];   // [wr][col]

  const int t = threadIdx.x;
  const int w = t >> 6, l = t & 63;
  const int wr = w >> 1, wc = w & 1;
  const int rl = l & 15, kg = l >> 4;   // kg selects this lane's 32B k-block

  // blockIdx -> upper triangle (rt <= ct), row-major enumeration
  const int bid = blockIdx.x;
  int rt = (int)((129.0f - sqrtf(129.0f * 129.0f - 8.0f * (float)bid)) * 0.5f);
  while (NTILE * rt - rt * (rt - 1) / 2 > bid) --rt;
  while (NTILE * (rt + 1) - (rt + 1) * rt / 2 <= bid) ++rt;
  const int ct = rt + (bid - (NTILE * rt - rt * (rt - 1) / 2));
  const int rowbase = rt * BM, colbase = ct * BM;

  // per-fragment global bases (proven operand layout: row ..+rl, bytes kg*32..+32)
  const u8* ap[4]; const u8* bp[4];
#pragma unroll
  for (int mi = 0; mi < 4; ++mi) {
    ap[mi] = zn8 + (size_t)(rowbase + wr * 64 + mi * 16 + rl) * DIM + kg * 32;
    bp[mi] = zn8 + (size_t)(colbase + wc * 64 + mi * 16 + rl) * DIM + kg * 32;
  }

  f32x4 acc[4][4];
#pragma unroll
  for (int i = 0; i < 4; ++i)
#pragma unroll
    for (int j = 0; j < 4; ++j) acc[i][j] = (f32x4){0.f, 0.f, 0.f, 0.f};

#pragma unroll
  for (int k = 0; k < 2; ++k) {
    i32x8 a[4], b[4];
#pragma unroll
    for (int mi = 0; mi < 4; ++mi) {
      i32x4 lo = *(const i32x4*)(ap[mi] + k * 128);
      i32x4 hi = *(const i32x4*)(ap[mi] + k * 128 + 16);
      a[mi] = __builtin_shufflevector(lo, hi, 0, 1, 2, 3, 4, 5, 6, 7);
    }
#pragma unroll
    for (int ni = 0; ni < 4; ++ni) {
      i32x4 lo = *(const i32x4*)(bp[ni] + k * 128);
      i32x4 hi = *(const i32x4*)(bp[ni] + k * 128 + 16);
      b[ni] = __builtin_shufflevector(lo, hi, 0, 1, 2, 3, 4, 5, 6, 7);
    }
#pragma unroll
    for (int mi = 0; mi < 4; ++mi)
#pragma unroll
      for (int ni = 0; ni < 4; ++ni)
        acc[mi][ni] = __builtin_amdgcn_mfma_scale_f32_16x16x128_f8f6f4(
            a[mi], b[ni], acc[mi][ni],
            0, 0,                      // cbsz=fp8, blgp=fp8
            0, 0x7f7f7f7f,             // opsel_a, scale_a = 1.0 (e8m0 127)
            0, 0x7f7f7f7f);            // opsel_b, scale_b = 1.0
  }

  // ---- epilogue: exp once, accumulate row-sums AND col-sums ----
  const int colg = l & 15, rowg = l >> 4;

  if (ct == rt + 32) {   // only these tiles contain positive pairs
#pragma unroll
    for (int mi = 0; mi < 4; ++mi)
#pragma unroll
      for (int j = 0; j < 4; ++j) {
        const int R = rowbase + wr * 64 + mi * 16 + rowg * 4 + j;
#pragma unroll
        for (int ni = 0; ni < 4; ++ni) {
          const int C = colbase + wc * 64 + ni * 16 + colg;
          if (C == R + BHALF) {
            float v = acc[mi][ni][j];
            pos[R] = v; pos[C] = v;
          }
        }
      }
  }

  float csum[4] = {0.f, 0.f, 0.f, 0.f};
  if (rt == ct) {   // diagonal tiles: exclude C==R
#pragma unroll
    for (int mi = 0; mi < 4; ++mi)
#pragma unroll
      for (int j = 0; j < 4; ++j) {
        const int R = rowbase + wr * 64 + mi * 16 + rowg * 4 + j;
        float s = 0.f;
#pragma unroll
        for (int ni = 0; ni < 4; ++ni) {
          const int C = colbase + wc * 64 + ni * 16 + colg;
          float e = (C != R) ? __expf(acc[mi][ni][j]) : 0.f;
          s += e; csum[ni] += e;
        }
        s = qp_add<0xB1>(s);           // xor 1 (quad_perm [1,0,3,2])
        s = qp_add<0x4E>(s);           // xor 2 (quad_perm [2,3,0,1])
        s += __shfl_xor(s, 4); s += __shfl_xor(s, 8);
        if (colg == 0)
          brs_rw[wc][wr * 64 + mi * 16 + rowg * 4 + j] = s;
      }
  } else {          // fast path: no masks
#pragma unroll
    for (int mi = 0; mi < 4; ++mi)
#pragma unroll
      for (int j = 0; j < 4; ++j) {
        float s = 0.f;
#pragma unroll
        for (int ni = 0; ni < 4; ++ni) {
          float e = __expf(acc[mi][ni][j]);
          s += e; csum[ni] += e;
        }
        s = qp_add<0xB1>(s);
        s = qp_add<0x4E>(s);
        s += __shfl_xor(s, 4); s += __shfl_xor(s, 8);
        if (colg == 0)
          brs_rw[wc][wr * 64 + mi * 16 + rowg * 4 + j] = s;
      }
  }
  // col-sums: reduce over the 4 row-lane groups (xor bits 4..5)
#pragma unroll
  for (int ni = 0; ni < 4; ++ni) {
    float cs = csum[ni];
    cs += __shfl_xor(cs, 16); cs += __shfl_xor(cs, 32);
    if (rowg == 0)
      brs_cw[wr][wc * 64 + ni * 16 + colg] = cs;
  }
  __syncthreads();
  if (t < BM) {
    partials[(size_t)ct * NROWS + rowbase + t] = brs_rw[0][t] + brs_rw[1][t];
    if (rt != ct)
      partials[(size_t)rt * NROWS + colbase + t] = brs_cw[0][t] + brs_cw[1][t];
  }
}

// Kernel 3: per-row lse - pos; per-block sums folded into one global atomic
// (out pre-zeroed by nrm_kernel; stream order guarantees visibility).
__global__ __launch_bounds__(256) void fin_kernel(const float* __restrict__ partials,
                                                  const float* __restrict__ pos,
                                                  float* __restrict__ out) {
  const int r = blockIdx.x * 256 + threadIdx.x;
  float s = 0.f;
#pragma unroll 8
  for (int ct = 0; ct < NTILE; ++ct) s += partials[(size_t)ct * NROWS + r];
  float v = logf(s) - pos[r];
#pragma unroll
  for (int m = 1; m < 64; m <<= 1) v += __shfl_xor(v, m);
  __shared__ float wsum[4];
  const int w = threadIdx.x >> 6, l = threadIdx.x & 63;
  if (l == 0) wsum[w] = v;
  __syncthreads();
  if (threadIdx.x == 0)
    atomicAdd(out, (wsum[0] + wsum[1] + wsum[2] + wsum[3]) * (1.f / NROWS));
}

extern "C" void kernel_launch(void* const* d_in, const int* in_sizes, int n_in,
                              void* d_out, int out_size, void* d_ws, size_t ws_size,
                              hipStream_t stream) {
  const float* zi = (const float*)d_in[0];
  const float* zj = (const float*)d_in[1];

  u8*    zn8      = (u8*)d_ws;                                             // 2 MB
  float* partials = (float*)((char*)d_ws + (size_t)NROWS * DIM);           // 2 MB
  float* pos      = (float*)((char*)partials + (size_t)NTILE * NROWS * 4); // 32 KB
  float* out      = (float*)d_out;

  nrm_kernel<<<NROWS / 4, 256, 0, stream>>>(zi, zj, zn8, out);
  sim_kernel<<<NTILE * (NTILE + 1) / 2, 256, 0, stream>>>(zn8, partials, pos);
  fin_kernel<<<NROWS / 256, 256, 0, stream>>>(partials, pos, out);
}

// Round 3
// 50.065 us; speedup vs baseline: 1.0355x; 1.0355x over previous
//
#include <hip/hip_runtime.h>

#define NROWS 8192
#define DIM   256          // elements per row == bytes per row in fp8
#define BHALF 4096
#define NTILE 64           // 8192 / 128
#define BM    128
#define NSTRIP 544         // sum over rt of ceil((64-rt)/4)
#define SQRT2 1.41421356237f

typedef unsigned char u8;
typedef __attribute__((ext_vector_type(4))) float f32x4;
typedef __attribute__((ext_vector_type(4))) int   i32x4;
typedef __attribute__((ext_vector_type(8))) int   i32x8;

__device__ inline void gload_lds16(const void* g, void* l) {
  __builtin_amdgcn_global_load_lds(
      (const __attribute__((address_space(1))) void*)g,
      (__attribute__((address_space(3))) void*)l, 16, 0, 0);
}

// exact xor-butterfly add via DPP quad_perm (VALU, not DS pipe)
template <int CTRL>
__device__ inline float qp_add(float s) {
  int si = __builtin_bit_cast(int, s);
  int v = __builtin_amdgcn_update_dpp(si, si, CTRL, 0xF, 0xF, false);
  return s + __builtin_bit_cast(float, v);
}

// Kernel 1: row-normalize concat(z_i, z_j), scale by sqrt(2) so dot = cos/TEMP,
// emit fp8 e4m3 Zn8 [8192][256] (2 MB). Also zeroes the output scalar.
__global__ __launch_bounds__(256) void nrm_kernel(const float* __restrict__ zi,
                                                  const float* __restrict__ zj,
                                                  u8* __restrict__ zn8,
                                                  float* __restrict__ out) {
  if (blockIdx.x == 0 && threadIdx.x == 0) out[0] = 0.f;
  const int w = threadIdx.x >> 6, l = threadIdx.x & 63;
  const int row = blockIdx.x * 4 + w;
  const float* src = (row < BHALF) ? zi + (size_t)row * DIM
                                   : zj + (size_t)(row - BHALF) * DIM;
  float4 v = *(const float4*)(src + l * 4);
  float ss = v.x * v.x + v.y * v.y + v.z * v.z + v.w * v.w;
#pragma unroll
  for (int m = 1; m < 64; m <<= 1) ss += __shfl_xor(ss, m);
  float inv = SQRT2 / fmaxf(sqrtf(ss), 1e-8f);
  int p = __builtin_amdgcn_cvt_pk_fp8_f32(v.x * inv, v.y * inv, 0, false);
  p = __builtin_amdgcn_cvt_pk_fp8_f32(v.z * inv, v.w * inv, p, true);
  *(int*)(zn8 + (size_t)row * DIM + (size_t)l * 4) = p;
}

// Kernel 2: strip-of-4 upper-triangle tiles per block. A-panel staged once ->
// registers; B-tiles stream through a 2x32KB LDS rotation with distance-2
// prefetch, counted vmcnt (never drained mid-strip), raw s_barriers only.
__global__ __launch_bounds__(256, 2) void sim_kernel(const u8* __restrict__ zn8,
                                                     float* __restrict__ partials,
                                                     float* __restrict__ pos) {
  __shared__ __align__(16) u8 Bsm[2][BM * DIM];   // 2 x 32 KB
  __shared__ float brs_rw[2][BM];                 // [wc][row] planes
  __shared__ float brs_cw[2][BM];                 // [wr][col] planes

  const int t = threadIdx.x;
  const int w = t >> 6, l = t & 63;
  const int wr = w >> 1, wc = w & 1;
  const int rl = l & 15, kg = l >> 4;
  const int colg = l & 15, rowg = l >> 4;

  // blockIdx -> (rt, ct0): strips of up to 4 column tiles per row panel
  const int bid = blockIdx.x;
  int acc_s = 0, rt = 0;
  for (; rt < NTILE; ++rt) {
    int s = (67 - rt) >> 2;               // ceil((64-rt)/4)
    if (bid < acc_s + s) break;
    acc_s += s;
  }
  const int ct0 = rt + ((bid - acc_s) << 2);
  const int nt = min(4, NTILE - ct0);
  const int rowbase = rt * BM;

  // stage a 128-row x 256B panel into LDS; linear dest, source chunk
  // inverse-swizzled with salt (row & 7) within each 128B half
  auto STAGE = [&](int base_row, u8* dst) {
#pragma unroll
    for (int i = 0; i < 8; ++i) {
      int c = i * 256 + t;                // 0..2047 16B-chunks
      int r = c >> 4, cd = c & 15;
      int cs = (cd & 8) | ((cd ^ r) & 7);
      gload_lds16(zn8 + (size_t)(base_row + r) * DIM + (size_t)cs * 16,
                  dst + (size_t)((i * 256 + w * 64) * 16));
    }
  };

  STAGE(rowbase, &Bsm[0][0]);             // A panel -> buf0 (8 loads)
  STAGE(ct0 * BM, &Bsm[1][0]);            // B(t0)   -> buf1 (8 loads)

  asm volatile("s_waitcnt vmcnt(8)" ::: "memory");   // A landed
  __builtin_amdgcn_sched_barrier(0);
  __builtin_amdgcn_s_barrier();
  __builtin_amdgcn_sched_barrier(0);

  // A fragments -> registers (64 VGPR), swizzled reads
  i32x8 a[4][2];
#pragma unroll
  for (int mi = 0; mi < 4; ++mi) {
    const int ra = wr * 64 + mi * 16 + rl;
    const int salt = ra & 7;
#pragma unroll
    for (int k = 0; k < 2; ++k) {
      i32x4 lo = *(const i32x4*)(&Bsm[0][0] + ra * DIM +
                                 ((k * 8 + ((kg * 2) ^ salt)) << 4));
      i32x4 hi = *(const i32x4*)(&Bsm[0][0] + ra * DIM +
                                 ((k * 8 + ((kg * 2 + 1) ^ salt)) << 4));
      a[mi][k] = __builtin_shufflevector(lo, hi, 0, 1, 2, 3, 4, 5, 6, 7);
    }
  }
  asm volatile("s_waitcnt lgkmcnt(0)" ::: "memory");
  __builtin_amdgcn_sched_barrier(0);
  __builtin_amdgcn_s_barrier();          // buf0 free for all waves
  __builtin_amdgcn_sched_barrier(0);

  if (nt > 1) STAGE((ct0 + 1) * BM, &Bsm[0][0]);     // B(t1) -> buf0

#pragma unroll
  for (int ti = 0; ti < 4; ++ti) {
    if (ti >= nt) break;
    const int ct = ct0 + ti;
    const int colbase = ct * BM;

    // B(ti) ready: my loads counted, then all waves'
    if (ti + 1 < nt) asm volatile("s_waitcnt vmcnt(8)" ::: "memory");
    else             asm volatile("s_waitcnt vmcnt(0)" ::: "memory");
    __builtin_amdgcn_sched_barrier(0);
    __builtin_amdgcn_s_barrier();
    __builtin_amdgcn_sched_barrier(0);

    const u8* Bb = &Bsm[(ti & 1) ^ 1][0];

    f32x4 acc[4][4];
#pragma unroll
    for (int i = 0; i < 4; ++i)
#pragma unroll
      for (int j = 0; j < 4; ++j) acc[i][j] = (f32x4){0.f, 0.f, 0.f, 0.f};

#pragma unroll
    for (int k = 0; k < 2; ++k) {
      i32x8 b[4];
#pragma unroll
      for (int ni = 0; ni < 4; ++ni) {
        const int rb = wc * 64 + ni * 16 + rl;
        const int salt = rb & 7;
        i32x4 lo = *(const i32x4*)(Bb + rb * DIM +
                                   ((k * 8 + ((kg * 2) ^ salt)) << 4));
        i32x4 hi = *(const i32x4*)(Bb + rb * DIM +
                                   ((k * 8 + ((kg * 2 + 1) ^ salt)) << 4));
        b[ni] = __builtin_shufflevector(lo, hi, 0, 1, 2, 3, 4, 5, 6, 7);
      }
#pragma unroll
      for (int mi = 0; mi < 4; ++mi)
#pragma unroll
        for (int ni = 0; ni < 4; ++ni)
          acc[mi][ni] = __builtin_amdgcn_mfma_scale_f32_16x16x128_f8f6f4(
              a[mi][k], b[ni], acc[mi][ni],
              0, 0,                      // cbsz=fp8, blgp=fp8
              0, 0x7f7f7f7f,             // scale_a = 1.0 (e8m0 127)
              0, 0x7f7f7f7f);            // scale_b = 1.0
    }

    // ---- per-tile epilogue ----
    if (ct == rt + 32) {   // tiles containing positive pairs
#pragma unroll
      for (int mi = 0; mi < 4; ++mi)
#pragma unroll
        for (int j = 0; j < 4; ++j) {
          const int R = rowbase + wr * 64 + mi * 16 + rowg * 4 + j;
#pragma unroll
          for (int ni = 0; ni < 4; ++ni) {
            const int C = colbase + wc * 64 + ni * 16 + colg;
            if (C == R + BHALF) {
              float v = acc[mi][ni][j];
              pos[R] = v; pos[C] = v;
            }
          }
        }
    }

    float csum[4] = {0.f, 0.f, 0.f, 0.f};
    if (rt == ct) {        // diagonal tile: exclude C==R
#pragma unroll
      for (int mi = 0; mi < 4; ++mi)
#pragma unroll
        for (int j = 0; j < 4; ++j) {
          const int R = rowbase + wr * 64 + mi * 16 + rowg * 4 + j;
          float s = 0.f;
#pragma unroll
          for (int ni = 0; ni < 4; ++ni) {
            const int C = colbase + wc * 64 + ni * 16 + colg;
            float e = (C != R) ? __expf(acc[mi][ni][j]) : 0.f;
            s += e; csum[ni] += e;
          }
          s = qp_add<0xB1>(s);           // xor 1
          s = qp_add<0x4E>(s);           // xor 2
          s += __shfl_xor(s, 4); s += __shfl_xor(s, 8);
          if (colg == 0)
            brs_rw[wc][wr * 64 + mi * 16 + rowg * 4 + j] = s;
        }
    } else {
#pragma unroll
      for (int mi = 0; mi < 4; ++mi)
#pragma unroll
        for (int j = 0; j < 4; ++j) {
          float s = 0.f;
#pragma unroll
          for (int ni = 0; ni < 4; ++ni) {
            float e = __expf(acc[mi][ni][j]);
            s += e; csum[ni] += e;
          }
          s = qp_add<0xB1>(s);
          s = qp_add<0x4E>(s);
          s += __shfl_xor(s, 4); s += __shfl_xor(s, 8);
          if (colg == 0)
            brs_rw[wc][wr * 64 + mi * 16 + rowg * 4 + j] = s;
        }
    }
#pragma unroll
    for (int ni = 0; ni < 4; ++ni) {
      float cs = csum[ni];
      cs += __shfl_xor(cs, 16); cs += __shfl_xor(cs, 32);
      if (rowg == 0)
        brs_cw[wr][wc * 64 + ni * 16 + colg] = cs;
    }

    asm volatile("s_waitcnt lgkmcnt(0)" ::: "memory");   // planes + frag reads done
    __builtin_amdgcn_sched_barrier(0);
    __builtin_amdgcn_s_barrier();        // buf[(ti&1)^1] free; planes visible
    __builtin_amdgcn_sched_barrier(0);

    if (ti + 2 < nt) STAGE((ct0 + ti + 2) * BM, &Bsm[(ti & 1) ^ 1][0]);

    if (t < BM) {
      partials[(size_t)ct * NROWS + rowbase + t] = brs_rw[0][t] + brs_rw[1][t];
    } else if (rt != ct) {
      const int c = t - BM;
      partials[(size_t)rt * NROWS + colbase + c] = brs_cw[0][c] + brs_cw[1][c];
    }
  }
}

// Kernel 3: per-row lse - pos; block sums folded into one global atomic
__global__ __launch_bounds__(256) void fin_kernel(const float* __restrict__ partials,
                                                  const float* __restrict__ pos,
                                                  float* __restrict__ out) {
  const int r = blockIdx.x * 256 + threadIdx.x;
  float s = 0.f;
#pragma unroll 8
  for (int ct = 0; ct < NTILE; ++ct) s += partials[(size_t)ct * NROWS + r];
  float v = logf(s) - pos[r];
#pragma unroll
  for (int m = 1; m < 64; m <<= 1) v += __shfl_xor(v, m);
  __shared__ float wsum[4];
  const int w = threadIdx.x >> 6, l = threadIdx.x & 63;
  if (l == 0) wsum[w] = v;
  __syncthreads();
  if (threadIdx.x == 0)
    atomicAdd(out, (wsum[0] + wsum[1] + wsum[2] + wsum[3]) * (1.f / NROWS));
}

extern "C" void kernel_launch(void* const* d_in, const int* in_sizes, int n_in,
                              void* d_out, int out_size, void* d_ws, size_t ws_size,
                              hipStream_t stream) {
  const float* zi = (const float*)d_in[0];
  const float* zj = (const float*)d_in[1];

  u8*    zn8      = (u8*)d_ws;                                             // 2 MB
  float* partials = (float*)((char*)d_ws + (size_t)NROWS * DIM);           // 2 MB
  float* pos      = (float*)((char*)partials + (size_t)NTILE * NROWS * 4); // 32 KB
  float* out      = (float*)d_out;

  nrm_kernel<<<NROWS / 4, 256, 0, stream>>>(zi, zj, zn8, out);
  sim_kernel<<<NSTRIP, 256, 0, stream>>>(zn8, partials, pos);
  fin_kernel<<<NROWS / 256, 256, 0, stream>>>(partials, pos, out);
}

// Round 4
// 32.593 us; speedup vs baseline: 1.5906x; 1.5361x over previous
//
#include <hip/hip_runtime.h>

#define NROWS 8192
#define DIM   256          // elements per row == bytes per row in fp8
#define BHALF 4096
#define NCHUNK 8           // col chunks per 128-row panel (1024 cols each)
#define SQRT2 1.41421356237f

typedef unsigned char u8;
typedef __attribute__((ext_vector_type(4))) float f32x4;
typedef __attribute__((ext_vector_type(4))) int   i32x4;
typedef __attribute__((ext_vector_type(8))) int   i32x8;

__device__ inline void gload_lds16(const void* g, void* l) {
  __builtin_amdgcn_global_load_lds(
      (const __attribute__((address_space(1))) void*)g,
      (__attribute__((address_space(3))) void*)l, 16, 0, 0);
}

// Kernel 1: row-normalize concat(z_i, z_j), scale by sqrt(2) so dot = cos/TEMP,
// emit fp8 e4m3 Zn8 [8192][256] (2 MB). Also zeroes the output scalar.
__global__ __launch_bounds__(256) void nrm_kernel(const float* __restrict__ zi,
                                                  const float* __restrict__ zj,
                                                  u8* __restrict__ zn8,
                                                  float* __restrict__ out) {
  if (blockIdx.x == 0 && threadIdx.x == 0) out[0] = 0.f;
  const int w = threadIdx.x >> 6, l = threadIdx.x & 63;
  const int row = blockIdx.x * 4 + w;
  const float* src = (row < BHALF) ? zi + (size_t)row * DIM
                                   : zj + (size_t)(row - BHALF) * DIM;
  float4 v = *(const float4*)(src + l * 4);
  float ss = v.x * v.x + v.y * v.y + v.z * v.z + v.w * v.w;
#pragma unroll
  for (int m = 1; m < 64; m <<= 1) ss += __shfl_xor(ss, m);
  float inv = SQRT2 / fmaxf(sqrtf(ss), 1e-8f);
  int p = __builtin_amdgcn_cvt_pk_fp8_f32(v.x * inv, v.y * inv, 0, false);
  p = __builtin_amdgcn_cvt_pk_fp8_f32(v.z * inv, v.w * inv, p, true);
  *(int*)(zn8 + (size_t)row * DIM + (size_t)l * 4) = p;
}

// Kernel 2: full-matrix row-sum sweep (no symmetry). Block = (panel rp, chunk ch):
// 128 panel rows x 1024 cols. Panel -> registers (B-operand); 8 col-tiles stream
// through 2x32KB LDS (A-operand), depth-2 prefetch, counted vmcnt. Operand swap
// makes output col = panel row = lane&15 -> row-sums are lane-local; one 8-shfl
// reduce per BLOCK. Diag skip / pos extract = cw==rw predicate in 1 tile each.
__global__ __launch_bounds__(256, 2) void sim_kernel(const u8* __restrict__ zn8,
                                                     float* __restrict__ partials,
                                                     float* __restrict__ pos) {
  __shared__ __align__(16) u8 Bsm[2][128 * DIM];   // 2 x 32 KB
  __shared__ float plane[2][128];

  const int t = threadIdx.x;
  const int w = t >> 6, l = t & 63;
  const int wa = w >> 1, wb = w & 1;    // wa: col 64-half, wb: panel-row 64-half
  const int rl = l & 15, kg = l >> 4;   // kg = lane's 32B k-block

  const int rp = (int)blockIdx.x >> 3;  // row panel 0..63
  const int ch = (int)blockIdx.x & 7;   // col chunk 0..7
  const int colbase = ch * 1024;        // zn8 row index of first streamed tile

  // stage 128 rows x 256B; linear dest, source chunk inverse-swizzled (salt r&7)
  auto STAGE = [&](int base_row, u8* dst) {
#pragma unroll
    for (int i = 0; i < 8; ++i) {
      int c = i * 256 + t;              // 0..2047 16B-chunks
      int r = c >> 4, cd = c & 15;
      int cs = (cd & 8) | ((cd ^ r) & 7);
      gload_lds16(zn8 + (size_t)(base_row + r) * DIM + (size_t)cs * 16,
                  dst + (size_t)((i * 256 + w * 64) * 16));
    }
  };
  // swizzled fragment read: 32B of row `row`, k-half k
  auto RD = [&](const u8* buf, int row, int k) -> i32x8 {
    const int salt = row & 7;
    i32x4 lo = *(const i32x4*)(buf + row * DIM + ((k * 8 + ((kg * 2) ^ salt)) << 4));
    i32x4 hi = *(const i32x4*)(buf + row * DIM + ((k * 8 + ((kg * 2 + 1) ^ salt)) << 4));
    return __builtin_shufflevector(lo, hi, 0, 1, 2, 3, 4, 5, 6, 7);
  };

  STAGE(rp * 128, &Bsm[0][0]);          // panel -> buf0 (8 loads)
  STAGE(colbase, &Bsm[1][0]);           // tile0 -> buf1 (8 loads)
  asm volatile("s_waitcnt vmcnt(8)" ::: "memory");   // panel landed
  __builtin_amdgcn_sched_barrier(0);
  __builtin_amdgcn_s_barrier();
  __builtin_amdgcn_sched_barrier(0);

  i32x8 pb[4][2];                       // panel fragments (B-operand), 64 VGPR
#pragma unroll
  for (int pj = 0; pj < 4; ++pj)
#pragma unroll
    for (int k = 0; k < 2; ++k)
      pb[pj][k] = RD(&Bsm[0][0], wb * 64 + pj * 16 + rl, k);
  asm volatile("s_waitcnt lgkmcnt(0)" ::: "memory");
  __builtin_amdgcn_sched_barrier(0);
  __builtin_amdgcn_s_barrier();         // buf0 free
  __builtin_amdgcn_sched_barrier(0);
  STAGE(colbase + 128, &Bsm[0][0]);     // tile1 -> buf0 (16 in flight)

  const int dtile = ((rp >> 3) == ch) ? (rp & 7) : -1;      // diag tile (local)
  const int pg = (rp < 32) ? (rp + 32) : (rp - 32);         // pos col-tile (global)
  const int ptile = ((pg >> 3) == ch) ? (pg & 7) : -1;      // pos tile (local)

  float rsum[4] = {0.f, 0.f, 0.f, 0.f};
  float pv[4]   = {0.f, 0.f, 0.f, 0.f};

#pragma unroll 2
  for (int ti = 0; ti < 8; ++ti) {
    // tile ti's 8 loads done (tile ti+1's 8 may stay in flight)
    if (ti < 7) asm volatile("s_waitcnt vmcnt(8)" ::: "memory");
    else        asm volatile("s_waitcnt vmcnt(0)" ::: "memory");
    __builtin_amdgcn_sched_barrier(0);
    __builtin_amdgcn_s_barrier();
    __builtin_amdgcn_sched_barrier(0);

    u8* Bb = &Bsm[(ti & 1) ^ 1][0];     // tile ti lives in buf[(ti+1)&1]

    i32x8 af[4][2];                     // streamed col-tile fragments (A-operand)
#pragma unroll
    for (int ci = 0; ci < 4; ++ci)
#pragma unroll
      for (int k = 0; k < 2; ++k)
        af[ci][k] = RD(Bb, wa * 64 + ci * 16 + rl, k);
    asm volatile("s_waitcnt lgkmcnt(0)" ::: "memory");
    __builtin_amdgcn_sched_barrier(0);
    __builtin_amdgcn_s_barrier();       // buffer free for restage
    __builtin_amdgcn_sched_barrier(0);
    if (ti < 6) STAGE(colbase + (ti + 2) * 128, Bb);

    f32x4 acc[4][4];
#pragma unroll
    for (int i = 0; i < 4; ++i)
#pragma unroll
      for (int j = 0; j < 4; ++j) acc[i][j] = (f32x4){0.f, 0.f, 0.f, 0.f};

#pragma unroll
    for (int k = 0; k < 2; ++k)
#pragma unroll
      for (int ci = 0; ci < 4; ++ci)
#pragma unroll
        for (int pj = 0; pj < 4; ++pj)
          acc[ci][pj] = __builtin_amdgcn_mfma_scale_f32_16x16x128_f8f6f4(
              af[ci][k], pb[pj][k], acc[ci][pj],
              0, 0,                      // cbsz=fp8, blgp=fp8
              0, 0x7f7f7f7f,             // scale_a = 1.0 (e8m0 127)
              0, 0x7f7f7f7f);            // scale_b = 1.0

    // epilogue: exp + lane-local row-sum accumulate (no cross-lane work)
    // output col (panel row) = pj*16 + (l&15); row (gram col) = ci*16 + kg*4 + jj
    if (ti == dtile) {                   // skip C==R (tile-diagonal)
#pragma unroll
      for (int ci = 0; ci < 4; ++ci)
#pragma unroll
        for (int pj = 0; pj < 4; ++pj)
#pragma unroll
          for (int jj = 0; jj < 4; ++jj) {
            float e = __expf(acc[ci][pj][jj]);
            bool skip = (wa == wb) && (ci == pj) && (kg == (rl >> 2)) && (jj == (rl & 3));
            rsum[pj] += skip ? 0.f : e;
          }
    } else {
#pragma unroll
      for (int ci = 0; ci < 4; ++ci)
#pragma unroll
        for (int pj = 0; pj < 4; ++pj)
#pragma unroll
          for (int jj = 0; jj < 4; ++jj)
            rsum[pj] += __expf(acc[ci][pj][jj]);
    }
    if (ti == ptile && wa == wb && kg == (rl >> 2)) {   // pos = tile-diagonal
#pragma unroll
      for (int ci = 0; ci < 4; ++ci) pv[ci] = acc[ci][ci][rl & 3];
    }
  }

  // reduce rsum over the 4 kg lane-groups (bits 4..5), once per block
#pragma unroll
  for (int pj = 0; pj < 4; ++pj) {
    rsum[pj] += __shfl_xor(rsum[pj], 16);
    rsum[pj] += __shfl_xor(rsum[pj], 32);
  }
  if (kg == 0) {
#pragma unroll
    for (int pj = 0; pj < 4; ++pj)
      plane[wa][wb * 64 + pj * 16 + rl] = rsum[pj];
  }
  __syncthreads();
  if (t < 128)
    partials[(size_t)ch * NROWS + rp * 128 + t] = plane[0][t] + plane[1][t];
  if (ptile >= 0 && wa == wb && kg == (rl >> 2)) {
#pragma unroll
    for (int ci = 0; ci < 4; ++ci)
      pos[rp * 128 + wb * 64 + ci * 16 + rl] = pv[ci];
  }
}

// Kernel 3: per-row lse - pos; block sums folded into one global atomic
// (out pre-zeroed by nrm_kernel; stream order guarantees visibility).
__global__ __launch_bounds__(256) void fin_kernel(const float* __restrict__ partials,
                                                  const float* __restrict__ pos,
                                                  float* __restrict__ out) {
  const int r = blockIdx.x * 256 + threadIdx.x;
  float s = 0.f;
#pragma unroll
  for (int ch = 0; ch < NCHUNK; ++ch) s += partials[(size_t)ch * NROWS + r];
  float v = logf(s) - pos[r];
#pragma unroll
  for (int m = 1; m < 64; m <<= 1) v += __shfl_xor(v, m);
  __shared__ float wsum[4];
  const int w = threadIdx.x >> 6, l = threadIdx.x & 63;
  if (l == 0) wsum[w] = v;
  __syncthreads();
  if (threadIdx.x == 0)
    atomicAdd(out, (wsum[0] + wsum[1] + wsum[2] + wsum[3]) * (1.f / NROWS));
}

extern "C" void kernel_launch(void* const* d_in, const int* in_sizes, int n_in,
                              void* d_out, int out_size, void* d_ws, size_t ws_size,
                              hipStream_t stream) {
  const float* zi = (const float*)d_in[0];
  const float* zj = (const float*)d_in[1];

  u8*    zn8      = (u8*)d_ws;                                              // 2 MB
  float* partials = (float*)((char*)d_ws + (size_t)NROWS * DIM);            // 256 KB
  float* pos      = (float*)((char*)partials + (size_t)NCHUNK * NROWS * 4); // 32 KB
  float* out      = (float*)d_out;

  nrm_kernel<<<NROWS / 4, 256, 0, stream>>>(zi, zj, zn8, out);
  sim_kernel<<<64 * NCHUNK, 256, 0, stream>>>(zn8, partials, pos);
  fin_kernel<<<NROWS / 256, 256, 0, stream>>>(partials, pos, out);
}

// Round 5
// 32.274 us; speedup vs baseline: 1.6063x; 1.0099x over previous
//
#include <hip/hip_runtime.h>

#define NROWS 8192
#define DIM   256          // elements per row == bytes per row in fp8
#define BHALF 4096
#define NCHUNK 8           // col chunks per 128-row panel (1024 cols each)
#define SCALE 1.69864358f  // sqrt(2 * log2(e)): dot = sim * log2(e)
#define LN2F  0.69314718f

typedef unsigned char u8;
typedef __attribute__((ext_vector_type(4))) float f32x4;
typedef __attribute__((ext_vector_type(4))) int   i32x4;
typedef __attribute__((ext_vector_type(8))) int   i32x8;

__device__ inline void gload_lds16(const void* g, void* l) {
  __builtin_amdgcn_global_load_lds(
      (const __attribute__((address_space(1))) void*)g,
      (__attribute__((address_space(3))) void*)l, 16, 0, 0);
}

// Kernel 1: row-normalize concat(z_i, z_j), scale by sqrt(2*log2e) so the fp8
// Gram dot = sim*log2e (exp2 instead of exp in the sum). Zeroes out scalar.
__global__ __launch_bounds__(256) void nrm_kernel(const float* __restrict__ zi,
                                                  const float* __restrict__ zj,
                                                  u8* __restrict__ zn8,
                                                  float* __restrict__ out) {
  if (blockIdx.x == 0 && threadIdx.x == 0) out[0] = 0.f;
  const int w = threadIdx.x >> 6, l = threadIdx.x & 63;
  const int row = blockIdx.x * 4 + w;
  const float* src = (row < BHALF) ? zi + (size_t)row * DIM
                                   : zj + (size_t)(row - BHALF) * DIM;
  float4 v = *(const float4*)(src + l * 4);
  float ss = v.x * v.x + v.y * v.y + v.z * v.z + v.w * v.w;
#pragma unroll
  for (int m = 1; m < 64; m <<= 1) ss += __shfl_xor(ss, m);
  float inv = SCALE / fmaxf(sqrtf(ss), 1e-8f);
  int p = __builtin_amdgcn_cvt_pk_fp8_f32(v.x * inv, v.y * inv, 0, false);
  p = __builtin_amdgcn_cvt_pk_fp8_f32(v.z * inv, v.w * inv, p, true);
  *(int*)(zn8 + (size_t)row * DIM + (size_t)l * 4) = p;
}

// Kernel 2: full-matrix row-sum sweep. Block = (panel rp, chunk ch). Panel ->
// registers (B-operand); 8 col-tiles stream through 2x32KB LDS, depth-1
// prefetch issued right after the tile barrier (ONE barrier per tile).
// Per-ci rolling pipeline: counted lgkmcnt(4), setprio'd 8-MFMA cluster,
// exp2 of ci overlapped with ci+1's MFMAs. Diag handled by exact subtract.
__global__ __launch_bounds__(256, 2) void sim_kernel(const u8* __restrict__ zn8,
                                                     float* __restrict__ partials,
                                                     float* __restrict__ pos) {
  __shared__ __align__(16) u8 Bsm[2][128 * DIM];   // 2 x 32 KB
  __shared__ float plane[2][128];

  const int t = threadIdx.x;
  const int w = t >> 6, l = t & 63;
  const int wa = w >> 1, wb = w & 1;    // wa: col 64-half, wb: panel-row 64-half
  const int rl = l & 15, kg = l >> 4;   // kg = lane's 32B k-block

  const int rp = (int)blockIdx.x >> 3;  // row panel 0..63
  const int ch = (int)blockIdx.x & 7;   // col chunk 0..7
  const int colbase = ch * 1024;        // zn8 row index of first streamed tile

  // stage 128 rows x 256B; linear dest, source chunk inverse-swizzled (salt r&7)
  auto STAGE = [&](int base_row, u8* dst) {
#pragma unroll
    for (int i = 0; i < 8; ++i) {
      int c = i * 256 + t;              // 0..2047 16B-chunks
      int r = c >> 4, cd = c & 15;
      int cs = (cd & 8) | ((cd ^ r) & 7);
      gload_lds16(zn8 + (size_t)(base_row + r) * DIM + (size_t)cs * 16,
                  dst + (size_t)((i * 256 + w * 64) * 16));
    }
  };
  // swizzled fragment read: 32B of row `row`, both k-halves (4 ds_read_b128)
  auto RD2 = [&](const u8* buf, int row, i32x8* dst) {
    const int salt = row & 7;
    const u8* base = buf + row * DIM;
#pragma unroll
    for (int k = 0; k < 2; ++k) {
      i32x4 lo = *(const i32x4*)(base + ((k * 8 + ((kg * 2) ^ salt)) << 4));
      i32x4 hi = *(const i32x4*)(base + ((k * 8 + ((kg * 2 + 1) ^ salt)) << 4));
      dst[k] = __builtin_shufflevector(lo, hi, 0, 1, 2, 3, 4, 5, 6, 7);
    }
  };

  STAGE(rp * 128, &Bsm[0][0]);          // panel -> buf0 (8 loads)
  STAGE(colbase, &Bsm[1][0]);           // tile0 -> buf1 (8 more, 16 in flight)
  asm volatile("s_waitcnt vmcnt(8)" ::: "memory");   // panel landed
  __builtin_amdgcn_sched_barrier(0);
  __builtin_amdgcn_s_barrier();
  __builtin_amdgcn_sched_barrier(0);

  i32x8 pb[4][2];                       // panel fragments (B-operand), 64 VGPR
#pragma unroll
  for (int pj = 0; pj < 4; ++pj)
    RD2(&Bsm[0][0], wb * 64 + pj * 16 + rl, pb[pj]);
  asm volatile("s_waitcnt lgkmcnt(0)" ::: "memory");
  __builtin_amdgcn_sched_barrier(0);
  // no barrier here: tile0's barrier below also proves all waves finished pb

  const int dtile = ((rp >> 3) == ch) ? (rp & 7) : -1;      // diag tile (local)
  const int pg = (rp < 32) ? (rp + 32) : (rp - 32);         // pos col-panel
  const int ptile = ((pg >> 3) == ch) ? (pg & 7) : -1;      // pos tile (local)

  float rsum[4] = {0.f, 0.f, 0.f, 0.f};
  float pv[4]   = {0.f, 0.f, 0.f, 0.f};
  const bool dlane = (wa == wb) && (kg == (rl >> 2));       // self-pair lanes

#pragma unroll 2
  for (int ti = 0; ti < 8; ++ti) {
    asm volatile("s_waitcnt vmcnt(0)" ::: "memory");  // tile ti landed (my part)
    __builtin_amdgcn_sched_barrier(0);
    __builtin_amdgcn_s_barrier();       // all waves: ti ready AND ti-1 readers done
    __builtin_amdgcn_sched_barrier(0);

    const u8* Bb = &Bsm[(ti + 1) & 1][0];              // tile ti's buffer
    if (ti < 7) STAGE(colbase + (ti + 1) * 128, &Bsm[ti & 1][0]);  // depth-1

    const bool tdiag = (ti == dtile), tpos = (ti == ptile);

    i32x8 af[2][2];                     // rolling streamed fragments
    RD2(Bb, wa * 64 + rl, af[0]);       // ci=0 (4 ds_reads in flight)
#pragma unroll
    for (int ci = 0; ci < 4; ++ci) {
      if (ci < 3) RD2(Bb, wa * 64 + (ci + 1) * 16 + rl, af[(ci + 1) & 1]);
      if (ci < 3) asm volatile("s_waitcnt lgkmcnt(4)" ::: "memory");
      else        asm volatile("s_waitcnt lgkmcnt(0)" ::: "memory");
      __builtin_amdgcn_sched_barrier(0);

      f32x4 acc[4];
#pragma unroll
      for (int pj = 0; pj < 4; ++pj) acc[pj] = (f32x4){0.f, 0.f, 0.f, 0.f};
      __builtin_amdgcn_s_setprio(1);
#pragma unroll
      for (int k = 0; k < 2; ++k)
#pragma unroll
        for (int pj = 0; pj < 4; ++pj)
          acc[pj] = __builtin_amdgcn_mfma_scale_f32_16x16x128_f8f6f4(
              af[ci & 1][k], pb[pj][k], acc[pj],
              0, 0,                      // cbsz=fp8, blgp=fp8
              0, 0x7f7f7f7f,             // scale_a = 1.0 (e8m0 127)
              0, 0x7f7f7f7f);            // scale_b = 1.0
      __builtin_amdgcn_s_setprio(0);

      // epilogue for this ci: exp2 + lane-local row-sum (overlaps next MFMAs)
#pragma unroll
      for (int pj = 0; pj < 4; ++pj)
#pragma unroll
        for (int jj = 0; jj < 4; ++jj)
          rsum[pj] += __builtin_amdgcn_exp2f(acc[pj][jj]);
      if (tdiag && dlane)                // exact removal of the self term
        rsum[ci] -= __builtin_amdgcn_exp2f(acc[ci][rl & 3]);
      if (tpos && dlane) pv[ci] = acc[ci][rl & 3];
    }
  }

  // reduce rsum over the 4 kg lane-groups (bits 4..5), once per block
#pragma unroll
  for (int pj = 0; pj < 4; ++pj) {
    rsum[pj] += __shfl_xor(rsum[pj], 16);
    rsum[pj] += __shfl_xor(rsum[pj], 32);
  }
  if (kg == 0) {
#pragma unroll
    for (int pj = 0; pj < 4; ++pj)
      plane[wa][wb * 64 + pj * 16 + rl] = rsum[pj];
  }
  __syncthreads();
  if (t < 128)
    partials[(size_t)ch * NROWS + rp * 128 + t] = plane[0][t] + plane[1][t];
  if (ptile >= 0 && dlane) {
#pragma unroll
    for (int ci = 0; ci < 4; ++ci)
      pos[rp * 128 + wb * 64 + ci * 16 + rl] = pv[ci] * LN2F;  // back to nats
  }
}

// Kernel 3: per-row lse - pos; block sums folded into one global atomic
// (out pre-zeroed by nrm_kernel; stream order guarantees visibility).
__global__ __launch_bounds__(256) void fin_kernel(const float* __restrict__ partials,
                                                  const float* __restrict__ pos,
                                                  float* __restrict__ out) {
  const int r = blockIdx.x * 256 + threadIdx.x;
  float s = 0.f;
#pragma unroll
  for (int ch = 0; ch < NCHUNK; ++ch) s += partials[(size_t)ch * NROWS + r];
  float v = logf(s) - pos[r];
#pragma unroll
  for (int m = 1; m < 64; m <<= 1) v += __shfl_xor(v, m);
  __shared__ float wsum[4];
  const int w = threadIdx.x >> 6, l = threadIdx.x & 63;
  if (l == 0) wsum[w] = v;
  __syncthreads();
  if (threadIdx.x == 0)
    atomicAdd(out, (wsum[0] + wsum[1] + wsum[2] + wsum[3]) * (1.f / NROWS));
}

extern "C" void kernel_launch(void* const* d_in, const int* in_sizes, int n_in,
                              void* d_out, int out_size, void* d_ws, size_t ws_size,
                              hipStream_t stream) {
  const float* zi = (const float*)d_in[0];
  const float* zj = (const float*)d_in[1];

  u8*    zn8      = (u8*)d_ws;                                              // 2 MB
  float* partials = (float*)((char*)d_ws + (size_t)NROWS * DIM);            // 256 KB
  float* pos      = (float*)((char*)partials + (size_t)NCHUNK * NROWS * 4); // 32 KB
  float* out      = (float*)d_out;

  nrm_kernel<<<NROWS / 4, 256, 0, stream>>>(zi, zj, zn8, out);
  sim_kernel<<<64 * NCHUNK, 256, 0, stream>>>(zn8, partials, pos);
  fin_kernel<<<NROWS / 256, 256, 0, stream>>>(partials, pos, out);
}